// Round 3
// baseline (2203.098 us; speedup 1.0000x reference)
//
#include <hip/hip_runtime.h>
#include <math.h>

#define HWQ 625      // 25*25
#define NPOSQ 390625 // 625*625
#define NB 4
#define NCH 1024

typedef __attribute__((ext_vector_type(8))) short bf16x8;
typedef __attribute__((ext_vector_type(4))) float f32x4;

__device__ inline unsigned short f2bf(float x) {
    union { float f; unsigned int u; } c; c.f = x;
    unsigned int u = c.u;
    return (unsigned short)((u + 0x7fffu + ((u >> 16) & 1u)) >> 16); // RNE
}

// ---------------- pack weights (direct + tap-permuted copies) ----------------
__global__ void pack_weights_kernel(
    const float* __restrict__ W1, const float* __restrict__ b1,
    const float* __restrict__ W2, const float* __restrict__ b2,
    const float* __restrict__ W3, const float* __restrict__ b3,
    float* __restrict__ WL1, float* __restrict__ WL3,
    float* __restrict__ bL1, float* __restrict__ bL2, float* __restrict__ bL3)
{
    int t = blockIdx.x * blockDim.x + threadIdx.x;
    if (t < 1620) { // WL1 [20][81]
        int co = t / 81, tap = t % 81;
        int d1 = tap / 27, d2 = (tap / 9) % 3, d3 = (tap / 3) % 3, d4 = tap % 3;
        int ptap = d3 * 27 + d4 * 9 + d1 * 3 + d2;
        WL1[t] = (co < 10) ? W1[co * 81 + tap] : W1[(co - 10) * 81 + ptap];
    }
    if (t < 1620) { // WL3 [2][1][10][81]
        int g = t / 810; int rem = t - g * 810;
        int ci = rem / 81; int tap = rem - ci * 81;
        int d1 = tap / 27, d2 = (tap / 9) % 3, d3 = (tap / 3) % 3, d4 = tap % 3;
        int ptap = d3 * 27 + d4 * 9 + d1 * 3 + d2;
        WL3[t] = W3[ci * 81 + (g == 0 ? tap : ptap)];
    }
    if (t < 20) { bL1[t] = b1[t % 10]; bL2[t] = b2[t % 10]; }
    if (t < 2)  { bL3[t] = b3[0]; }
}

// ---------------- pack layer-2 weights into MFMA A-fragment order ----------------
// Ablob layout: frag = ((g*3 + kstep)*9 + d3d4), each frag = 64 lanes x 8 bf16.
// A[row=co=lane&15][k = kstep*32 + (lane>>4)*8 + j], k indexes cie = ci*9 + e.
__global__ void pack_mfma_w2_kernel(const float* __restrict__ W2,
                                    unsigned short* __restrict__ Ablob)
{
    int t = blockIdx.x * blockDim.x + threadIdx.x;
    if (t >= 54 * 64) return;
    int frag = t >> 6, lane = t & 63;
    int g = frag / 27; int r1 = frag % 27; int kstep = r1 / 9; int dd = r1 % 9;
    int d3 = dd / 3, d4 = dd % 3;
    int co = lane & 15;
    unsigned short v[8];
#pragma unroll
    for (int j = 0; j < 8; ++j) {
        int k = kstep * 32 + ((lane >> 4) << 3) + j;
        float w = 0.0f;
        if (co < 10 && k < 90) {
            int ci = k / 9, e = k % 9, d1 = e / 3, d2 = e % 3;
            int tap = (g == 0) ? (d1 * 27 + d2 * 9 + d3 * 3 + d4)
                               : (d3 * 27 + d4 * 9 + d1 * 3 + d2);
            w = W2[(co * 10 + ci) * 81 + tap];
        }
        v[j] = f2bf(w);
    }
    uint4* dst = (uint4*)(Ablob + (size_t)frag * 512 + lane * 8);
    uint4 val;
    val.x = (unsigned)v[0] | ((unsigned)v[1] << 16);
    val.y = (unsigned)v[2] | ((unsigned)v[3] << 16);
    val.z = (unsigned)v[4] | ((unsigned)v[5] << 16);
    val.w = (unsigned)v[6] | ((unsigned)v[7] << 16);
    *dst = val;
}

// ---------------- inverse L2 norms over channel dim ----------------
__global__ void invnorm_kernel(const float* __restrict__ fA, const float* __restrict__ fB,
                               float* __restrict__ invA, float* __restrict__ invB)
{
    int idx = blockIdx.x * blockDim.x + threadIdx.x;
    if (idx >= NB * HWQ) return;
    const float* f = blockIdx.y ? fB : fA;
    float* o = blockIdx.y ? invB : invA;
    int b = idx / HWQ, m = idx - b * HWQ;
    const float* p = f + (size_t)b * NCH * HWQ + m;
    float s = 0.f;
    for (int c = 0; c < NCH; c += 4) {
        float x0 = p[(c + 0) * HWQ], x1 = p[(c + 1) * HWQ];
        float x2 = p[(c + 2) * HWQ], x3 = p[(c + 3) * HWQ];
        s += x0 * x0 + x1 * x1 + x2 * x2 + x3 * x3;
    }
    o[idx] = 1.0f / sqrtf(s + 1e-6f);
}

// ---------------- correlation GEMM ----------------
__global__ __launch_bounds__(256) void corr_gemm_kernel(
    const float* __restrict__ fA, const float* __restrict__ fB,
    const float* __restrict__ invA, const float* __restrict__ invB,
    float* __restrict__ corr)
{
    __shared__ float As[16][64];
    __shared__ float Bs[16][64];
    const int b = blockIdx.z;
    const int m0 = blockIdx.y * 64, n0 = blockIdx.x * 64;
    const int tid = threadIdx.x;
    const int tx = tid & 15, ty = tid >> 4;
    float acc[4][4] = {};
    const float* Ab = fA + (size_t)b * NCH * HWQ;
    const float* Bb = fB + (size_t)b * NCH * HWQ;
    for (int k0 = 0; k0 < NCH; k0 += 16) {
        for (int i = tid; i < 1024; i += 256) {
            int k = i >> 6, mm = i & 63;
            int gm = m0 + mm, gn = n0 + mm;
            As[k][mm] = (gm < HWQ) ? Ab[(k0 + k) * HWQ + gm] : 0.0f;
            Bs[k][mm] = (gn < HWQ) ? Bb[(k0 + k) * HWQ + gn] : 0.0f;
        }
        __syncthreads();
#pragma unroll
        for (int k = 0; k < 16; ++k) {
            float4 a4 = *(const float4*)&As[k][ty * 4];
            float4 b4 = *(const float4*)&Bs[k][tx * 4];
            float av[4] = {a4.x, a4.y, a4.z, a4.w};
            float bv[4] = {b4.x, b4.y, b4.z, b4.w};
#pragma unroll
            for (int i = 0; i < 4; ++i)
#pragma unroll
                for (int j = 0; j < 4; ++j)
                    acc[i][j] = fmaf(av[i], bv[j], acc[i][j]);
        }
        __syncthreads();
    }
#pragma unroll
    for (int i = 0; i < 4; ++i) {
        int m = m0 + ty * 4 + i;
        if (m >= HWQ) continue;
        float ia = invA[b * HWQ + m];
#pragma unroll
        for (int j = 0; j < 4; ++j) {
            int n = n0 + tx * 4 + j;
            if (n >= HWQ) continue;
            float v = acc[i][j] * ia * invB[b * HWQ + n];
            v = fmaxf(v, 0.0f);
            v = v / sqrtf(v * v + 1e-6f);
            corr[((size_t)b * HWQ + m) * HWQ + n] = v;
        }
    }
}

// ---------------- mutual matching helpers ----------------
__global__ void rowmax_kernel(const float* __restrict__ s, float* __restrict__ rmax)
{
    int row = blockIdx.x * 4 + (threadIdx.x >> 6);
    int lane = threadIdx.x & 63;
    if (row >= NB * HWQ) return;
    const float* p = s + (size_t)row * HWQ;
    float v = -1e30f;
    for (int n = lane; n < HWQ; n += 64) v = fmaxf(v, p[n]);
    for (int off = 32; off; off >>= 1) v = fmaxf(v, __shfl_xor(v, off));
    if (lane == 0) rmax[row] = v;
}

__global__ void colmax_kernel(const float* __restrict__ s, float* __restrict__ cmax)
{
    int b = blockIdx.x;
    int col = blockIdx.y * 128 + threadIdx.x;
    if (col >= HWQ) return;
    const float* p = s + (size_t)b * NPOSQ + col;
    float v = -1e30f;
    for (int m = 0; m < HWQ; ++m) v = fmaxf(v, p[m * HWQ]);
    cmax[b * HWQ + col] = v;
}

__global__ void mm_apply_kernel(const float* __restrict__ s, const float* __restrict__ rmax,
                                const float* __restrict__ cmax, float* __restrict__ out)
{
    int idx = blockIdx.x * blockDim.x + threadIdx.x;
    if (idx >= NB * NPOSQ) return;
    int b = idx / NPOSQ, rem = idx - b * NPOSQ;
    int m = rem / HWQ, n = rem - m * HWQ;
    float v = s[idx];
    out[idx] = v * v * v / ((rmax[b * HWQ + m] + 1e-5f) * (cmax[b * HWQ + n] + 1e-5f));
}

__global__ void sum2_kernel(const float* __restrict__ x3, float* __restrict__ s)
{
    int idx = blockIdx.x * blockDim.x + threadIdx.x;
    if (idx >= NB * NPOSQ) return;
    int b = idx / NPOSQ, rem = idx - b * NPOSQ;
    s[idx] = x3[(size_t)(b * 2) * NPOSQ + rem] + x3[(size_t)(b * 2 + 1) * NPOSQ + rem];
}

// ---------------- conv4d VALU (layers 1 & 3): 2x2 (f3,f4) tile per thread ----------------
template <int CIN_G, int COUT_G>
__global__ __launch_bounds__(192) void conv4d_kernel(
    const float* __restrict__ in, const float* __restrict__ w,
    const float* __restrict__ bias, float* __restrict__ out)
{
    __shared__ float sp[9 * 784]; // 9 x 28 x 28
    const int f12 = blockIdx.x;
    const int g = blockIdx.y;
    const int f1 = f12 / 25, f2 = f12 - f1 * 25;
    const int tid = threadIdx.x;

    for (int i = tid; i < 9 * 784; i += 192) sp[i] = 0.0f;

    const int tt = (tid < 169) ? tid : 0;
    const int ty = tt / 13, tx = tt - ty * 13;
    const int r0 = ty * 2, c0 = tx * 2;

    float acc[COUT_G][4];
#pragma unroll
    for (int co = 0; co < COUT_G; ++co) {
        float bv = bias[g * COUT_G + co];
        acc[co][0] = bv; acc[co][1] = bv; acc[co][2] = bv; acc[co][3] = bv;
    }

#pragma unroll 1
    for (int ci = 0; ci < CIN_G; ++ci) {
        const float* ip = in + (size_t)(g * CIN_G + ci) * NPOSQ;
        __syncthreads();
        for (int i = tid; i < 5625; i += 192) {
            int e = i / 625, q = i - e * 625;
            int d1 = e / 3, d2 = e - d1 * 3;
            int f1n = f1 + d1 - 1, f2n = f2 + d2 - 1;
            float v = 0.0f;
            if (((unsigned)f1n < 25u) & ((unsigned)f2n < 25u))
                v = ip[(f1n * 25 + f2n) * HWQ + q];
            int rr = q / 25, cc = q - rr * 25;
            sp[e * 784 + (rr + 1) * 28 + (cc + 1)] = v;
        }
        __syncthreads();
        const float* wci = w + ((size_t)(g * COUT_G) * CIN_G + ci) * 81;
#pragma unroll 1
        for (int e = 0; e < 9; ++e) {
            float win[16];
            const int base = e * 784 + r0 * 28 + c0;
#pragma unroll
            for (int a = 0; a < 4; ++a)
#pragma unroll
                for (int bb = 0; bb < 4; ++bb)
                    win[a * 4 + bb] = sp[base + a * 28 + bb];
#pragma unroll
            for (int co = 0; co < COUT_G; ++co) {
                const float* wp = wci + (size_t)co * CIN_G * 81 + e * 9;
#pragma unroll
                for (int d3 = 0; d3 < 3; ++d3)
#pragma unroll
                    for (int d4 = 0; d4 < 3; ++d4) {
                        float wv = wp[d3 * 3 + d4];
                        acc[co][0] = fmaf(win[d3 * 4 + d4],           wv, acc[co][0]);
                        acc[co][1] = fmaf(win[d3 * 4 + d4 + 1],       wv, acc[co][1]);
                        acc[co][2] = fmaf(win[(d3 + 1) * 4 + d4],     wv, acc[co][2]);
                        acc[co][3] = fmaf(win[(d3 + 1) * 4 + d4 + 1], wv, acc[co][3]);
                    }
            }
        }
    }

    if (tid < 169) {
#pragma unroll
        for (int co = 0; co < COUT_G; ++co) {
            float* op = out + (size_t)(g * COUT_G + co) * NPOSQ + f12 * 625;
#pragma unroll
            for (int i = 0; i < 2; ++i)
#pragma unroll
                for (int j = 0; j < 2; ++j) {
                    int f3 = r0 + i, f4 = c0 + j;
                    if (f3 < 25 && f4 < 25)
                        op[f3 * 25 + f4] = fmaxf(acc[co][i * 2 + j], 0.0f);
                }
        }
    }
}

// ---------------- conv4d layer2 via MFMA (bf16 inputs/weights, fp32 accum) ----------
// Per block: one (f1,f2), one group g. D[co(16; 10 used)][q-tile(16)] accumulated
// over K = 90 (ci,e) x 9 shifted (d3,d4) GEMMs. LDS: transposed staging
// [q_pad=764 rows][40 k-slots] bf16, 80B row stride (20-bank lane stride,
// conflict-free, 16B aligned for ds_read_b128).
__global__ __launch_bounds__(512) void conv4d_mfma_l2(
    const float* __restrict__ in,             // [20][NPOSQ] batch slab
    const unsigned short* __restrict__ Ablob, // packed A-fragments
    const float* __restrict__ bias,           // [20]
    float* __restrict__ out)                  // [20][NPOSQ]
{
    __shared__ alignas(16) unsigned short sp[764 * 40]; // 61120 B
    const int f12 = blockIdx.x;
    const int g = blockIdx.y;
    const int f1 = f12 / 25, f2 = f12 - f1 * 25;
    const int tid = threadIdx.x;
    const int wave = tid >> 6, lane = tid & 63;
    const int lo16 = lane & 15, k0grp = (lane >> 4) << 3; // 0,8,16,24

    f32x4 acc[7];
#pragma unroll
    for (int j = 0; j < 7; ++j) acc[j] = (f32x4){0.f, 0.f, 0.f, 0.f};

    const unsigned short* Ag = Ablob + (size_t)g * 27 * 512;

    for (int kstep = 0; kstep < 3; ++kstep) {
        __syncthreads(); // previous kstep's reads done before overwrite
        // stage 4 k-slots per wave: LDS[qp][k_local] = bf16(plane value)
        for (int i = 0; i < 4; ++i) {
            int k_local = wave * 4 + i;
            int cie = kstep * 32 + k_local;
            if (cie < 90) {
                int ci = cie / 9, e = cie % 9;
                int f1n = f1 + e / 3 - 1, f2n = f2 + e % 3 - 1;
                bool pl = ((unsigned)f1n < 25u) & ((unsigned)f2n < 25u);
                const float* pp = in + (size_t)(g * 10 + ci) * NPOSQ + (f1n * 25 + f2n) * 625;
                for (int pass = 0; pass < 12; ++pass) {
                    int qp = pass * 64 + lane;
                    if (qp < 756) {
                        int u = qp / 28, v = qp - u * 28;
                        float val = 0.0f;
                        if (pl & (u >= 1) & (u <= 25) & (v >= 1) & (v <= 25))
                            val = pp[(u - 1) * 25 + (v - 1)];
                        sp[qp * 40 + k_local] = f2bf(val);
                    }
                }
            }
        }
        __syncthreads();
        for (int dd = 0; dd < 9; ++dd) {
            int d3 = dd / 3, d4 = dd - d3 * 3;
            bf16x8 afrag = *(const bf16x8*)(Ag + ((size_t)kstep * 9 + dd) * 512 + lane * 8);
            int t = wave;
#pragma unroll
            for (int j = 0; j < 7; ++j) {
                if (t < 50) { // wave-uniform
                    int f3 = t >> 1, h = t & 1;
                    int col = (f3 + d3) * 28 + h * 16 + d4 + lo16;
                    bf16x8 bfrag = *(const bf16x8*)(sp + col * 40 + k0grp);
                    acc[j] = __builtin_amdgcn_mfma_f32_16x16x32_bf16(afrag, bfrag, acc[j], 0, 0, 0);
                }
                t += 8;
            }
        }
    }

    // store: D col = lane&15 -> f4 within half-tile; row = (lane>>4)*4 + r -> co
    int t = wave;
    for (int j = 0; j < 7; ++j) {
        if (t < 50) {
            int f3 = t >> 1, h = t & 1;
            int f4 = h * 16 + lo16;
            if (f4 < 25) {
#pragma unroll
                for (int r = 0; r < 4; ++r) {
                    int co = (lane >> 4) * 4 + r;
                    if (co < 10) {
                        float v = acc[j][r] + bias[g * 10 + co];
                        out[(size_t)(g * 10 + co) * NPOSQ + f12 * 625 + f3 * 25 + f4] =
                            fmaxf(v, 0.0f);
                    }
                }
            }
        }
        t += 8;
    }
}

// ---------------- launch ----------------
extern "C" void kernel_launch(void* const* d_in, const int* in_sizes, int n_in,
                              void* d_out, int out_size, void* d_ws, size_t ws_size,
                              hipStream_t stream)
{
    const float* fA = (const float*)d_in[0];
    const float* fB = (const float*)d_in[1];
    const float* W1 = (const float*)d_in[2];
    const float* b1 = (const float*)d_in[3];
    const float* W2 = (const float*)d_in[4];
    const float* b2 = (const float*)d_in[5];
    const float* W3 = (const float*)d_in[6];
    const float* b3 = (const float*)d_in[7];
    float* out = (float*)d_out;
    float* ws = (float*)d_ws;

    float* invA = ws + 0;        // 2500
    float* invB = ws + 2500;     // 2500
    float* rmax = ws + 5000;     // 2500
    float* cmax = ws + 7500;     // 2500
    float* WL1  = ws + 10000;    // 1620
    float* WL3  = ws + 27820;    // 1620
    float* bL1  = ws + 29440;    // 20
    float* bL2  = ws + 29460;    // 20
    float* bL3  = ws + 29480;    // 2
    float* corr = ws + 40000;    // 1562500
    float* sbuf = ws + 1602504;  // 1562500
    float* x1   = ws + 3170000;  // 7812500  (20ch, one batch)
    float* x2   = ws + 11000000; // 7812500  (20ch, one batch)
    float* x3   = ws + 18820000; // 3125000  ([B][2][NPOSQ])
    unsigned short* Ablob = (unsigned short*)(ws + 21950000); // 27648 ushort

    hipLaunchKernelGGL(pack_weights_kernel, dim3(64), dim3(256), 0, stream,
                       W1, b1, W2, b2, W3, b3, WL1, WL3, bL1, bL2, bL3);
    hipLaunchKernelGGL(pack_mfma_w2_kernel, dim3(14), dim3(256), 0, stream, W2, Ablob);
    hipLaunchKernelGGL(invnorm_kernel, dim3(10, 2), dim3(256), 0, stream, fA, fB, invA, invB);
    hipLaunchKernelGGL(corr_gemm_kernel, dim3(10, 10, 4), dim3(256), 0, stream,
                       fA, fB, invA, invB, corr);
    hipLaunchKernelGGL(rowmax_kernel, dim3(625), dim3(256), 0, stream, corr, rmax);
    hipLaunchKernelGGL(colmax_kernel, dim3(4, 5), dim3(128), 0, stream, corr, cmax);
    hipLaunchKernelGGL(mm_apply_kernel, dim3(6104), dim3(256), 0, stream, corr, rmax, cmax, corr);

    for (int b = 0; b < NB; ++b) {
        hipLaunchKernelGGL((conv4d_kernel<1, 20>), dim3(625, 1), dim3(192), 0, stream,
                           corr + (size_t)b * NPOSQ, WL1, bL1, x1);
        hipLaunchKernelGGL(conv4d_mfma_l2, dim3(625, 2), dim3(512), 0, stream,
                           x1, Ablob, bL2, x2);
        hipLaunchKernelGGL((conv4d_kernel<10, 1>), dim3(625, 2), dim3(192), 0, stream,
                           x2, WL3, bL3, x3 + (size_t)b * 2 * NPOSQ);
    }

    hipLaunchKernelGGL(sum2_kernel, dim3(6104), dim3(256), 0, stream, x3, sbuf);
    hipLaunchKernelGGL(rowmax_kernel, dim3(625), dim3(256), 0, stream, sbuf, rmax);
    hipLaunchKernelGGL(colmax_kernel, dim3(4, 5), dim3(128), 0, stream, sbuf, cmax);
    hipLaunchKernelGGL(mm_apply_kernel, dim3(6104), dim3(256), 0, stream, sbuf, rmax, cmax, out);
}

// Round 4
// 1066.730 us; speedup vs baseline: 2.0653x; 2.0653x over previous
//
#include <hip/hip_runtime.h>
#include <math.h>

#define HWQ 625      // 25*25
#define NPOSQ 390625 // 625*625
#define NB 4
#define NCH 1024

typedef __attribute__((ext_vector_type(8))) short bf16x8;
typedef __attribute__((ext_vector_type(4))) float f32x4;

__device__ inline unsigned short f2bf(float x) {
    union { float f; unsigned int u; } c; c.f = x;
    unsigned int u = c.u;
    return (unsigned short)((u + 0x7fffu + ((u >> 16) & 1u)) >> 16); // RNE
}

// ---------------- pack: W1P [9e][9t][20co], bias dups ----------------
__global__ void pack_misc_kernel(const float* __restrict__ W1, const float* __restrict__ b1,
                                 const float* __restrict__ b2,
                                 float* __restrict__ W1P, float* __restrict__ bL1,
                                 float* __restrict__ bL2)
{
    int t = blockIdx.x * blockDim.x + threadIdx.x;
    if (t < 1620) {
        int co = t % 20; int r = t / 20; int e = r / 9, t34 = r % 9;
        // direct group: tap = e*9+t34 ; permuted group: tap = t34*9+e
        W1P[t] = (co < 10) ? W1[co * 81 + e * 9 + t34] : W1[(co - 10) * 81 + t34 * 9 + e];
    }
    if (t < 20) { bL1[t] = b1[t % 10]; bL2[t] = b2[t % 10]; }
}

// ---------------- pack layer-2 weights into MFMA A-fragment order ----------------
// frag = ((g*3 + kstep)*9 + dd); A[row=co=lane&15][k=kstep*32+(lane>>4)*8+j], k=ci*9+e
__global__ void pack_mfma_w2_kernel(const float* __restrict__ W2,
                                    unsigned short* __restrict__ Ablob)
{
    int t = blockIdx.x * blockDim.x + threadIdx.x;
    if (t >= 54 * 64) return;
    int frag = t >> 6, lane = t & 63;
    int g = frag / 27; int r1 = frag % 27; int kstep = r1 / 9; int dd = r1 % 9;
    int d3 = dd / 3, d4 = dd % 3;
    int co = lane & 15;
    unsigned short v[8];
#pragma unroll
    for (int j = 0; j < 8; ++j) {
        int k = kstep * 32 + ((lane >> 4) << 3) + j;
        float w = 0.0f;
        if (co < 10 && k < 90) {
            int ci = k / 9, e = k % 9, d1 = e / 3, d2 = e % 3;
            int tap = (g == 0) ? (d1 * 27 + d2 * 9 + d3 * 3 + d4)
                               : (d3 * 27 + d4 * 9 + d1 * 3 + d2);
            w = W2[(co * 10 + ci) * 81 + tap];
        }
        v[j] = f2bf(w);
    }
    uint4 val;
    val.x = (unsigned)v[0] | ((unsigned)v[1] << 16);
    val.y = (unsigned)v[2] | ((unsigned)v[3] << 16);
    val.z = (unsigned)v[4] | ((unsigned)v[5] << 16);
    val.w = (unsigned)v[6] | ((unsigned)v[7] << 16);
    *(uint4*)(Ablob + (size_t)frag * 512 + lane * 8) = val;
}

// ---------------- pack layer-3 weights: K=180 (both groups), rows 0/1 ----------------
// frag = kstep*9 + dd (kstep<6). A[row][k]: row0 <-> k<90 (g0), row1 <-> k>=90 (g1).
__global__ void pack_mfma_w3_kernel(const float* __restrict__ W3,
                                    unsigned short* __restrict__ Ablob3)
{
    int t = blockIdx.x * blockDim.x + threadIdx.x;
    if (t >= 54 * 64) return;
    int frag = t >> 6, lane = t & 63;
    int kstep = frag / 9, dd = frag % 9;
    int d3 = dd / 3, d4 = dd % 3;
    int row = lane & 15;
    unsigned short v[8];
#pragma unroll
    for (int j = 0; j < 8; ++j) {
        int k = kstep * 32 + ((lane >> 4) << 3) + j;
        float w = 0.0f;
        if (k < 180) {
            int g = k / 90, rem = k - g * 90;
            int ci = rem / 9, e = rem % 9;
            if (row == g) {
                int d1 = e / 3, d2 = e % 3;
                int tap = (g == 0) ? (d1 * 27 + d2 * 9 + d3 * 3 + d4)
                                   : (d3 * 27 + d4 * 9 + d1 * 3 + d2);
                w = W3[ci * 81 + tap];
            }
        }
        v[j] = f2bf(w);
    }
    uint4 val;
    val.x = (unsigned)v[0] | ((unsigned)v[1] << 16);
    val.y = (unsigned)v[2] | ((unsigned)v[3] << 16);
    val.z = (unsigned)v[4] | ((unsigned)v[5] << 16);
    val.w = (unsigned)v[6] | ((unsigned)v[7] << 16);
    *(uint4*)(Ablob3 + (size_t)frag * 512 + lane * 8) = val;
}

// ---------------- inverse L2 norms over channel dim ----------------
__global__ void invnorm_kernel(const float* __restrict__ fA, const float* __restrict__ fB,
                               float* __restrict__ invA, float* __restrict__ invB)
{
    int idx = blockIdx.x * blockDim.x + threadIdx.x;
    if (idx >= NB * HWQ) return;
    const float* f = blockIdx.y ? fB : fA;
    float* o = blockIdx.y ? invB : invA;
    int b = idx / HWQ, m = idx - b * HWQ;
    const float* p = f + (size_t)b * NCH * HWQ + m;
    float s = 0.f;
    for (int c = 0; c < NCH; c += 4) {
        float x0 = p[(c + 0) * HWQ], x1 = p[(c + 1) * HWQ];
        float x2 = p[(c + 2) * HWQ], x3 = p[(c + 3) * HWQ];
        s += x0 * x0 + x1 * x1 + x2 * x2 + x3 * x3;
    }
    o[idx] = 1.0f / sqrtf(s + 1e-6f);
}

// ---------------- correlation GEMM ----------------
__global__ __launch_bounds__(256) void corr_gemm_kernel(
    const float* __restrict__ fA, const float* __restrict__ fB,
    const float* __restrict__ invA, const float* __restrict__ invB,
    float* __restrict__ corr)
{
    __shared__ float As[16][64];
    __shared__ float Bs[16][64];
    const int b = blockIdx.z;
    const int m0 = blockIdx.y * 64, n0 = blockIdx.x * 64;
    const int tid = threadIdx.x;
    const int tx = tid & 15, ty = tid >> 4;
    float acc[4][4] = {};
    const float* Ab = fA + (size_t)b * NCH * HWQ;
    const float* Bb = fB + (size_t)b * NCH * HWQ;
    for (int k0 = 0; k0 < NCH; k0 += 16) {
        for (int i = tid; i < 1024; i += 256) {
            int k = i >> 6, mm = i & 63;
            int gm = m0 + mm, gn = n0 + mm;
            As[k][mm] = (gm < HWQ) ? Ab[(k0 + k) * HWQ + gm] : 0.0f;
            Bs[k][mm] = (gn < HWQ) ? Bb[(k0 + k) * HWQ + gn] : 0.0f;
        }
        __syncthreads();
#pragma unroll
        for (int k = 0; k < 16; ++k) {
            float4 a4 = *(const float4*)&As[k][ty * 4];
            float4 b4 = *(const float4*)&Bs[k][tx * 4];
            float av[4] = {a4.x, a4.y, a4.z, a4.w};
            float bv[4] = {b4.x, b4.y, b4.z, b4.w};
#pragma unroll
            for (int i = 0; i < 4; ++i)
#pragma unroll
                for (int j = 0; j < 4; ++j)
                    acc[i][j] = fmaf(av[i], bv[j], acc[i][j]);
        }
        __syncthreads();
    }
#pragma unroll
    for (int i = 0; i < 4; ++i) {
        int m = m0 + ty * 4 + i;
        if (m >= HWQ) continue;
        float ia = invA[b * HWQ + m];
#pragma unroll
        for (int j = 0; j < 4; ++j) {
            int n = n0 + tx * 4 + j;
            if (n >= HWQ) continue;
            float v = acc[i][j] * ia * invB[b * HWQ + n];
            v = fmaxf(v, 0.0f);
            v = v / sqrtf(v * v + 1e-6f);
            corr[((size_t)b * HWQ + m) * HWQ + n] = v;
        }
    }
}

// ---------------- mutual matching helpers ----------------
__global__ void rowmax_kernel(const float* __restrict__ s, float* __restrict__ rmax)
{
    int row = blockIdx.x * 4 + (threadIdx.x >> 6);
    int lane = threadIdx.x & 63;
    if (row >= NB * HWQ) return;
    const float* p = s + (size_t)row * HWQ;
    float v = -1e30f;
    for (int n = lane; n < HWQ; n += 64) v = fmaxf(v, p[n]);
    for (int off = 32; off; off >>= 1) v = fmaxf(v, __shfl_xor(v, off));
    if (lane == 0) rmax[row] = v;
}

__global__ void colmax_kernel(const float* __restrict__ s, float* __restrict__ cmax)
{
    int b = blockIdx.x;
    int col = blockIdx.y * 128 + threadIdx.x;
    if (col >= HWQ) return;
    const float* p = s + (size_t)b * NPOSQ + col;
    float v = -1e30f;
    for (int m = 0; m < HWQ; ++m) v = fmaxf(v, p[m * HWQ]);
    cmax[b * HWQ + col] = v;
}

__global__ void mm_apply_kernel(const float* __restrict__ s, const float* __restrict__ rmax,
                                const float* __restrict__ cmax, float* __restrict__ out)
{
    int idx = blockIdx.x * blockDim.x + threadIdx.x;
    if (idx >= NB * NPOSQ) return;
    int b = idx / NPOSQ, rem = idx - b * NPOSQ;
    int m = rem / HWQ, n = rem - m * HWQ;
    float v = s[idx];
    out[idx] = v * v * v / ((rmax[b * HWQ + m] + 1e-5f) * (cmax[b * HWQ + n] + 1e-5f));
}

// ---------------- layer 1: VALU conv, weights in LDS, bf16 out ----------------
__global__ __launch_bounds__(192) void conv4d_l1(
    const float* __restrict__ corr, const float* __restrict__ W1P,
    const float* __restrict__ bL1, unsigned short* __restrict__ x1)
{
    __shared__ float sp[9 * 784]; // 9 x 28 x 28
    __shared__ float wl[1620];
    const int f12 = blockIdx.x;
    const float* in = corr + (size_t)blockIdx.z * NPOSQ;
    unsigned short* out = x1 + (size_t)blockIdx.z * 20 * NPOSQ;
    const int f1 = f12 / 25, f2 = f12 - f1 * 25;
    const int tid = threadIdx.x;

    for (int i = tid; i < 9 * 784; i += 192) sp[i] = 0.0f;
    for (int i = tid; i < 1620; i += 192) wl[i] = W1P[i];

    const int tt = (tid < 169) ? tid : 0;
    const int ty = tt / 13, tx = tt - ty * 13;
    const int r0 = ty * 2, c0 = tx * 2;

    float acc[20][4];
#pragma unroll
    for (int co = 0; co < 20; ++co) {
        float bv = bL1[co];
        acc[co][0] = bv; acc[co][1] = bv; acc[co][2] = bv; acc[co][3] = bv;
    }

    __syncthreads();
    for (int i = tid; i < 5625; i += 192) {
        int e = i / 625, q = i - e * 625;
        int d1 = e / 3, d2 = e - d1 * 3;
        int f1n = f1 + d1 - 1, f2n = f2 + d2 - 1;
        float v = 0.0f;
        if (((unsigned)f1n < 25u) & ((unsigned)f2n < 25u))
            v = in[(f1n * 25 + f2n) * HWQ + q];
        int rr = q / 25, cc = q - rr * 25;
        sp[e * 784 + (rr + 1) * 28 + (cc + 1)] = v;
    }
    __syncthreads();

#pragma unroll 1
    for (int e = 0; e < 9; ++e) {
        float win[16];
        const int base = e * 784 + r0 * 28 + c0;
#pragma unroll
        for (int a = 0; a < 4; ++a)
#pragma unroll
            for (int bb = 0; bb < 4; ++bb)
                win[a * 4 + bb] = sp[base + a * 28 + bb];
#pragma unroll
        for (int t34 = 0; t34 < 9; ++t34) {
            int d3 = t34 / 3, d4 = t34 - d3 * 3;
            float x0 = win[d3 * 4 + d4], x1v = win[d3 * 4 + d4 + 1];
            float x2v = win[(d3 + 1) * 4 + d4], x3v = win[(d3 + 1) * 4 + d4 + 1];
            const float* wp = wl + (e * 9 + t34) * 20;
#pragma unroll
            for (int c4 = 0; c4 < 5; ++c4) {
                float4 w4 = *(const float4*)(wp + c4 * 4);
                float wv[4] = {w4.x, w4.y, w4.z, w4.w};
#pragma unroll
                for (int q4 = 0; q4 < 4; ++q4) {
                    int co = c4 * 4 + q4;
                    acc[co][0] = fmaf(x0, wv[q4], acc[co][0]);
                    acc[co][1] = fmaf(x1v, wv[q4], acc[co][1]);
                    acc[co][2] = fmaf(x2v, wv[q4], acc[co][2]);
                    acc[co][3] = fmaf(x3v, wv[q4], acc[co][3]);
                }
            }
        }
    }

    if (tid < 169) {
#pragma unroll
        for (int co = 0; co < 20; ++co) {
            unsigned short* op = out + (size_t)co * NPOSQ + f12 * 625;
#pragma unroll
            for (int i = 0; i < 2; ++i)
#pragma unroll
                for (int j = 0; j < 2; ++j) {
                    int f3 = r0 + i, f4 = c0 + j;
                    if (f3 < 25 && f4 < 25)
                        op[f3 * 25 + f4] = f2bf(fmaxf(acc[co][i * 2 + j], 0.0f));
                }
        }
    }
}

// ---------------- MFMA conv core (layers 2 & 3) ----------------
// LDS: halo grid rows = u*27+v (u,v in 0..26 <-> f3,f4 in -1..25), 736 rows x 36 k-slots bf16.
// B-frag col = (f3+d3)*27 + d4 + h*16 + lo16 ; row-wrap garbage only feeds f4>=25 (never stored).
#define L2S 36
#define L2ROWS 736

__global__ __launch_bounds__(512, 6) void conv4d_mfma_l2(
    const unsigned short* __restrict__ x1, const unsigned short* __restrict__ Ablob,
    const float* __restrict__ bL2, unsigned short* __restrict__ x2)
{
    __shared__ alignas(16) unsigned short sp[L2ROWS * L2S]; // 52992 B
    const int f12 = blockIdx.x, g = blockIdx.y;
    const unsigned short* in = x1 + (size_t)blockIdx.z * 20 * NPOSQ;
    unsigned short* out = x2 + (size_t)blockIdx.z * 20 * NPOSQ;
    const int f1 = f12 / 25, f2 = f12 - f1 * 25;
    const int tid = threadIdx.x, wave = tid >> 6, lane = tid & 63;
    const int lo16 = lane & 15, kqg = (lane >> 4) << 3;
    const int kg = tid & 3;

    f32x4 acc[7];
#pragma unroll
    for (int j = 0; j < 7; ++j) acc[j] = (f32x4){0.f, 0.f, 0.f, 0.f};
    const unsigned short* Ag = Ablob + (size_t)g * 27 * 512;

#pragma unroll 1
    for (int kstep = 0; kstep < 3; ++kstep) {
        unsigned poff[8];
        unsigned vmask = 0;
        const int kbase = kstep * 32 + kg * 8;
#pragma unroll
        for (int j = 0; j < 8; ++j) {
            int cie = kbase + j;
            int ci = cie / 9, e = cie - ci * 9;
            int f1n = f1 + e / 3 - 1, f2n = f2 + e % 3 - 1;
            if ((cie < 90) & ((unsigned)f1n < 25u) & ((unsigned)f2n < 25u)) vmask |= (1u << j);
            poff[j] = (unsigned)((g * 10 + ci) * NPOSQ + (f1n * 25 + f2n) * 625);
        }
        __syncthreads();
        for (int task = tid; task < 2916; task += 512) {
            int qp = task >> 2;
            int u = qp / 27, v = qp - u * 27;
            int f3i = u - 1, f4i = v - 1;
            bool inq = ((unsigned)f3i < 25u) & ((unsigned)f4i < 25u);
            int qoff = f3i * 25 + f4i;
            unsigned short vals[8];
#pragma unroll
            for (int j = 0; j < 8; ++j)
                vals[j] = (inq && ((vmask >> j) & 1)) ? in[poff[j] + qoff] : (unsigned short)0;
            unsigned short* dst = sp + qp * L2S + kg * 8;
            uint2 w0, w1;
            w0.x = (unsigned)vals[0] | ((unsigned)vals[1] << 16);
            w0.y = (unsigned)vals[2] | ((unsigned)vals[3] << 16);
            w1.x = (unsigned)vals[4] | ((unsigned)vals[5] << 16);
            w1.y = (unsigned)vals[6] | ((unsigned)vals[7] << 16);
            *(uint2*)dst = w0;
            *(uint2*)(dst + 4) = w1;
        }
        __syncthreads();
        bf16x8 afA = *(const bf16x8*)(Ag + (size_t)(kstep * 9) * 512 + lane * 8);
#pragma unroll 1
        for (int dd = 0; dd < 9; ++dd) {
            bf16x8 afN = (dd < 8) ? *(const bf16x8*)(Ag + (size_t)(kstep * 9 + dd + 1) * 512 + lane * 8) : afA;
            int d3 = dd / 3, d4 = dd - d3 * 3;
            int t = wave;
#pragma unroll
            for (int j = 0; j < 7; ++j, t += 8) {
                if (t < 50) {
                    int f3 = t >> 1, h = t & 1;
                    int col = (f3 + d3) * 27 + d4 + h * 16 + lo16;
                    const unsigned short* bp = sp + col * L2S + kqg;
                    uint2 p0 = *(const uint2*)bp;
                    uint2 p1 = *(const uint2*)(bp + 4);
                    union { unsigned u[4]; bf16x8 v; } cv;
                    cv.u[0] = p0.x; cv.u[1] = p0.y; cv.u[2] = p1.x; cv.u[3] = p1.y;
                    acc[j] = __builtin_amdgcn_mfma_f32_16x16x32_bf16(afA, cv.v, acc[j], 0, 0, 0);
                }
            }
            afA = afN;
        }
    }

    int t = wave;
    for (int j = 0; j < 7; ++j, t += 8) {
        if (t < 50) {
            int f3 = t >> 1, h = t & 1;
            int f4 = h * 16 + lo16;
            if (f4 < 25) {
#pragma unroll
                for (int r = 0; r < 4; ++r) {
                    int co = (lane >> 4) * 4 + r;
                    if (co < 10) {
                        float v = acc[j][r] + bL2[g * 10 + co];
                        out[(size_t)(g * 10 + co) * NPOSQ + f12 * 625 + f3 * 25 + f4] =
                            f2bf(fmaxf(v, 0.0f));
                    }
                }
            }
        }
    }
}

// Layer 3: K=192 (both groups), fused relu-sum, fp32 out to sbuf.
__global__ __launch_bounds__(512, 6) void conv4d_mfma_l3(
    const unsigned short* __restrict__ x2, const unsigned short* __restrict__ Ablob3,
    const float* __restrict__ b3p, float* __restrict__ sbuf)
{
    __shared__ alignas(16) unsigned short sp[L2ROWS * L2S];
    const int f12 = blockIdx.x;
    const unsigned short* in = x2 + (size_t)blockIdx.z * 20 * NPOSQ;
    float* out = sbuf + (size_t)blockIdx.z * NPOSQ;
    const int f1 = f12 / 25, f2 = f12 - f1 * 25;
    const int tid = threadIdx.x, wave = tid >> 6, lane = tid & 63;
    const int lo16 = lane & 15, kqg = (lane >> 4) << 3;
    const int kg = tid & 3;

    f32x4 acc[7];
#pragma unroll
    for (int j = 0; j < 7; ++j) acc[j] = (f32x4){0.f, 0.f, 0.f, 0.f};

#pragma unroll 1
    for (int kstep = 0; kstep < 6; ++kstep) {
        unsigned poff[8];
        unsigned vmask = 0;
        const int kbase = kstep * 32 + kg * 8;
#pragma unroll
        for (int j = 0; j < 8; ++j) {
            int cie = kbase + j;
            int plane = cie / 9, e = cie - plane * 9;
            int f1n = f1 + e / 3 - 1, f2n = f2 + e % 3 - 1;
            if ((cie < 180) & ((unsigned)f1n < 25u) & ((unsigned)f2n < 25u)) vmask |= (1u << j);
            poff[j] = (unsigned)(plane * NPOSQ + (f1n * 25 + f2n) * 625);
        }
        __syncthreads();
        for (int task = tid; task < 2916; task += 512) {
            int qp = task >> 2;
            int u = qp / 27, v = qp - u * 27;
            int f3i = u - 1, f4i = v - 1;
            bool inq = ((unsigned)f3i < 25u) & ((unsigned)f4i < 25u);
            int qoff = f3i * 25 + f4i;
            unsigned short vals[8];
#pragma unroll
            for (int j = 0; j < 8; ++j)
                vals[j] = (inq && ((vmask >> j) & 1)) ? in[poff[j] + qoff] : (unsigned short)0;
            unsigned short* dst = sp + qp * L2S + kg * 8;
            uint2 w0, w1;
            w0.x = (unsigned)vals[0] | ((unsigned)vals[1] << 16);
            w0.y = (unsigned)vals[2] | ((unsigned)vals[3] << 16);
            w1.x = (unsigned)vals[4] | ((unsigned)vals[5] << 16);
            w1.y = (unsigned)vals[6] | ((unsigned)vals[7] << 16);
            *(uint2*)dst = w0;
            *(uint2*)(dst + 4) = w1;
        }
        __syncthreads();
        bf16x8 afA = *(const bf16x8*)(Ablob3 + (size_t)(kstep * 9) * 512 + lane * 8);
#pragma unroll 1
        for (int dd = 0; dd < 9; ++dd) {
            bf16x8 afN = (dd < 8) ? *(const bf16x8*)(Ablob3 + (size_t)(kstep * 9 + dd + 1) * 512 + lane * 8) : afA;
            int d3 = dd / 3, d4 = dd - d3 * 3;
            int t = wave;
#pragma unroll
            for (int j = 0; j < 7; ++j, t += 8) {
                if (t < 50) {
                    int f3 = t >> 1, h = t & 1;
                    int col = (f3 + d3) * 27 + d4 + h * 16 + lo16;
                    const unsigned short* bp = sp + col * L2S + kqg;
                    uint2 p0 = *(const uint2*)bp;
                    uint2 p1 = *(const uint2*)(bp + 4);
                    union { unsigned u[4]; bf16x8 v; } cv;
                    cv.u[0] = p0.x; cv.u[1] = p0.y; cv.u[2] = p1.x; cv.u[3] = p1.y;
                    acc[j] = __builtin_amdgcn_mfma_f32_16x16x32_bf16(afA, cv.v, acc[j], 0, 0, 0);
                }
            }
            afA = afN;
        }
    }

    const float b3v = b3p[0];
    if ((lane >> 4) == 0) {
        int t = wave;
        for (int j = 0; j < 7; ++j, t += 8) {
            if (t < 50) {
                int f3 = t >> 1, h = t & 1;
                int f4 = h * 16 + lo16;
                if (f4 < 25) {
                    float s0 = fmaxf(acc[j][0] + b3v, 0.0f);
                    float s1 = fmaxf(acc[j][1] + b3v, 0.0f);
                    out[f12 * 625 + f3 * 25 + f4] = s0 + s1;
                }
            }
        }
    }
}

// ---------------- launch ----------------
extern "C" void kernel_launch(void* const* d_in, const int* in_sizes, int n_in,
                              void* d_out, int out_size, void* d_ws, size_t ws_size,
                              hipStream_t stream)
{
    const float* fA = (const float*)d_in[0];
    const float* fB = (const float*)d_in[1];
    const float* W1 = (const float*)d_in[2];
    const float* b1 = (const float*)d_in[3];
    const float* W2 = (const float*)d_in[4];
    const float* b2 = (const float*)d_in[5];
    const float* W3 = (const float*)d_in[6];
    const float* b3 = (const float*)d_in[7];
    float* out = (float*)d_out;
    float* ws = (float*)d_ws;

    float* invA = ws + 0;        // 2500
    float* invB = ws + 2500;     // 2500
    float* rmax = ws + 5000;     // 2500
    float* cmax = ws + 7500;     // 2500
    float* W1P  = ws + 10000;    // 1620
    float* bL1  = ws + 11620;    // 20
    float* bL2  = ws + 11640;    // 20
    unsigned short* Ablob2 = (unsigned short*)(ws + 12000); // 27648 us = 13824 fl
    unsigned short* Ablob3 = (unsigned short*)(ws + 25824); // 27648 us = 13824 fl
    float* corr = ws + 40000;    // 1562500
    float* sbuf = ws + 1602500;  // 1562500
    unsigned short* x1b = (unsigned short*)(ws + 3165000);

    // fused path needs: x1b,x2b full-batch (15.625M fl each) -> end 34,415,000 floats
    const size_t REQ = (size_t)34415000 * 4;
    const bool fused = ws_size >= REQ;
    unsigned short* x2b = fused ? (unsigned short*)(ws + 18790000)
                                : (unsigned short*)(ws + 7080000);

    hipLaunchKernelGGL(pack_misc_kernel, dim3(7), dim3(256), 0, stream, W1, b1, b2, W1P, bL1, bL2);
    hipLaunchKernelGGL(pack_mfma_w2_kernel, dim3(14), dim3(256), 0, stream, W2, Ablob2);
    hipLaunchKernelGGL(pack_mfma_w3_kernel, dim3(14), dim3(256), 0, stream, W3, Ablob3);
    hipLaunchKernelGGL(invnorm_kernel, dim3(10, 2), dim3(256), 0, stream, fA, fB, invA, invB);
    hipLaunchKernelGGL(corr_gemm_kernel, dim3(10, 10, 4), dim3(256), 0, stream,
                       fA, fB, invA, invB, corr);
    hipLaunchKernelGGL(rowmax_kernel, dim3(625), dim3(256), 0, stream, corr, rmax);
    hipLaunchKernelGGL(colmax_kernel, dim3(4, 5), dim3(128), 0, stream, corr, cmax);
    hipLaunchKernelGGL(mm_apply_kernel, dim3(6104), dim3(256), 0, stream, corr, rmax, cmax, corr);

    if (fused) {
        hipLaunchKernelGGL(conv4d_l1, dim3(625, 1, NB), dim3(192), 0, stream, corr, W1P, bL1, x1b);
        hipLaunchKernelGGL(conv4d_mfma_l2, dim3(625, 2, NB), dim3(512), 0, stream,
                           x1b, Ablob2, bL2, x2b);
        hipLaunchKernelGGL(conv4d_mfma_l3, dim3(625, 1, NB), dim3(512), 0, stream,
                           x2b, Ablob3, b3, sbuf);
    } else {
        for (int b = 0; b < NB; ++b) {
            hipLaunchKernelGGL(conv4d_l1, dim3(625, 1, 1), dim3(192), 0, stream,
                               corr + (size_t)b * NPOSQ, W1P, bL1, x1b);
            hipLaunchKernelGGL(conv4d_mfma_l2, dim3(625, 2, 1), dim3(512), 0, stream,
                               x1b, Ablob2, bL2, x2b);
            hipLaunchKernelGGL(conv4d_mfma_l3, dim3(625, 1, 1), dim3(512), 0, stream,
                               x2b, Ablob3, b3, sbuf + (size_t)b * NPOSQ);
        }
    }

    hipLaunchKernelGGL(rowmax_kernel, dim3(625), dim3(256), 0, stream, sbuf, rmax);
    hipLaunchKernelGGL(colmax_kernel, dim3(4, 5), dim3(128), 0, stream, sbuf, cmax);
    hipLaunchKernelGGL(mm_apply_kernel, dim3(6104), dim3(256), 0, stream, sbuf, rmax, cmax, out);
}